// Round 2
// baseline (102.059 us; speedup 1.0000x reference)
//
#include <hip/hip_runtime.h>

// MaxSel: max over 4 directional 3x3 Laplacians, zero-padded, 48x 512x512 fp32.
// Wave-per-row-strip layout: each 64-lane wave covers the full 512-col width
// (8 floats/lane), producing RS=8 output rows from a rolling 3-row register
// window over RS+2=10 input rows. Horizontal halos via __shfl (no scalar halo
// loads); vertical redundancy 10/8 = 1.25x.
// NOTE: plain stores only — __builtin_nontemporal_store interacted with the
// harness's poison-fill L2 lines (stale-line readback after re-poison).

#define HH 512
#define WW 512
#define IMG (HH * WW)
#define RS 8                    // output rows per wave-strip
#define STRIPS (HH / RS)        // 64 strips per image

typedef float f32x4 __attribute__((ext_vector_type(4)));

struct Row {
    float c[8];   // lane's 8 contiguous columns (32B aligned)
    float l, r;   // halo: col-1 and col+8 (from neighbor lanes via shfl)
};

__device__ __forceinline__ float getv(const Row& rw, int j) {
    // j in [-1, 8]; resolved at compile time under full unroll
    if (j < 0) return rw.l;
    if (j > 7) return rw.r;
    return rw.c[j];
}

__global__ __launch_bounds__(256) void lapmax_kernel(const float* __restrict__ x,
                                                     float* __restrict__ out,
                                                     int ntasks) {
    // Bijective XCD-aware swizzle (m204 form): consecutive logical strips share
    // 2 halo rows; keep them on the same XCD's L2.
    const int nblk = gridDim.x;
    const int q = nblk >> 3, rr = nblk & 7;
    const int xcd = blockIdx.x & 7, idx = blockIdx.x >> 3;
    const int lb = (xcd < rr ? xcd * (q + 1) : rr * (q + 1) + (xcd - rr) * q) + idx;

    const int lane = threadIdx.x & 63;
    const int task = (lb << 2) + (threadIdx.x >> 6);   // 4 waves per block
    if (task >= ntasks) return;

    const int img   = task / STRIPS;
    const int strip = task % STRIPS;
    const int h0  = strip * RS;
    const int col = lane << 3;                         // 8 cols/lane, wave = 512 cols

    const float* __restrict__ base  = x   + (size_t)img * IMG + col;
    float* __restrict__       obase = out + (size_t)img * IMG + col;

    Row rows[3];

#pragma unroll
    for (int k = 0; k < RS + 2; ++k) {
        const int r = h0 - 1 + k;
        Row& rw = rows[k % 3];
        if (r >= 0 && r < HH) {            // wave-uniform branch (r uniform per wave)
            const float* p = base + (size_t)r * WW;
            const f32x4 a = *reinterpret_cast<const f32x4*>(p);
            const f32x4 b = *reinterpret_cast<const f32x4*>(p + 4);
            rw.c[0] = a[0]; rw.c[1] = a[1]; rw.c[2] = a[2]; rw.c[3] = a[3];
            rw.c[4] = b[0]; rw.c[5] = b[1]; rw.c[6] = b[2]; rw.c[7] = b[3];
            // Horizontal halo from neighbor lanes; lane 0 / lane 63 are the
            // true image edges -> zero pad.
            const float lv = __shfl_up(rw.c[7], 1);
            const float rv = __shfl_down(rw.c[0], 1);
            rw.l = (lane == 0)  ? 0.0f : lv;
            rw.r = (lane == 63) ? 0.0f : rv;
        } else {
#pragma unroll
            for (int j = 0; j < 8; ++j) rw.c[j] = 0.0f;
            rw.l = 0.0f; rw.r = 0.0f;
        }

        if (k >= 2) {
            const Row& up  = rows[(k - 2) % 3];
            const Row& mid = rows[(k - 1) % 3];
            const Row& dn  = rows[k % 3];
            float o[8];
#pragma unroll
            for (int j = 0; j < 8; ++j) {
                const float sh  = getv(mid, j - 1) + getv(mid, j + 1); // horizontal
                const float sv  = up.c[j] + dn.c[j];                   // vertical
                const float sd1 = getv(up, j + 1) + getv(dn, j - 1);   // anti-diag
                const float sd2 = getv(up, j - 1) + getv(dn, j + 1);   // main diag
                const float m = fmaxf(fmaxf(sh, sv), fmaxf(sd1, sd2));
                o[j] = fmaf(-2.0f, mid.c[j], m);
            }
            float* po = obase + (size_t)(h0 + k - 2) * WW;
            *reinterpret_cast<f32x4*>(po)     = f32x4{ o[0], o[1], o[2], o[3] };
            *reinterpret_cast<f32x4*>(po + 4) = f32x4{ o[4], o[5], o[6], o[7] };
        }
    }
}

extern "C" void kernel_launch(void* const* d_in, const int* in_sizes, int n_in,
                              void* d_out, int out_size, void* d_ws, size_t ws_size,
                              hipStream_t stream) {
    const float* x = (const float*)d_in[0];
    float* out = (float*)d_out;

    const int total  = in_sizes[0];           // nimg * 512 * 512 elements
    const int nimg   = total / IMG;           // 48
    const int ntasks = nimg * STRIPS;         // wave-strips (3072 for 48 images)
    const int blocks = (ntasks + 3) / 4;      // 4 waves per 256-thread block (768)

    lapmax_kernel<<<blocks, 256, 0, stream>>>(x, out, ntasks);
}